// Round 10
// baseline (418.154 us; speedup 1.0000x reference)
//
#include <hip/hip_runtime.h>
#include <stdint.h>

typedef unsigned short u16;
typedef __attribute__((ext_vector_type(8))) short bf16x8;
typedef __attribute__((ext_vector_type(8))) unsigned short u16x8;
typedef __attribute__((ext_vector_type(4))) unsigned short u16x4;
typedef __attribute__((ext_vector_type(4))) float f32x4;

#define AS1 __attribute__((address_space(1)))
#define AS3 __attribute__((address_space(3)))

__device__ __forceinline__ u16 f32_to_bf16(float f) {
  unsigned int u = __builtin_bit_cast(unsigned int, f);
  u += 0x7FFFu + ((u >> 16) & 1u);
  return (u16)(u >> 16);
}
__device__ __forceinline__ float bf16_to_f32(u16 s) {
  return __builtin_bit_cast(float, (unsigned int)s << 16);
}
__device__ __forceinline__ void g2lds16(const void* g, void* l) {
  __builtin_amdgcn_global_load_lds((const AS1 void*)g, (AS3 void*)l, 16, 0, 0);
}

// ---------------- conversions ----------------
// grid-stride: 2048 blocks x 256 thr x 64 elems = 33,554,432 (exact)
__global__ __launch_bounds__(256) void cvt_x(const float* __restrict__ x, u16* __restrict__ xb) {
  size_t base = ((size_t)blockIdx.x * 256 + threadIdx.x) * 8;
  const size_t stride = (size_t)2048 * 256 * 8;
  #pragma unroll
  for (int it = 0; it < 8; ++it, base += stride) {
    float4 a = *(const float4*)(x + base);
    float4 b = *(const float4*)(x + base + 4);
    u16x8 o;
    o[0]=f32_to_bf16(a.x); o[1]=f32_to_bf16(a.y); o[2]=f32_to_bf16(a.z); o[3]=f32_to_bf16(a.w);
    o[4]=f32_to_bf16(b.x); o[5]=f32_to_bf16(b.y); o[6]=f32_to_bf16(b.z); o[7]=f32_to_bf16(b.w);
    *(u16x8*)(xb + base) = o;
  }
}

// WT[z][n][k] = W_z[k][n], bf16.  4 matrices of 1024x1024.
__global__ void cvt_wt(const float* __restrict__ Wq, const float* __restrict__ Wk,
                       const float* __restrict__ Wv, const float* __restrict__ Wo,
                       u16* __restrict__ WT) {
  __shared__ float tile[32][33];
  const float* W = blockIdx.z==0 ? Wq : blockIdx.z==1 ? Wk : blockIdx.z==2 ? Wv : Wo;
  int n0 = blockIdx.x*32, k0 = blockIdx.y*32;
  int tx = threadIdx.x, ty = threadIdx.y;
  for (int r = ty; r < 32; r += 8)
    tile[r][tx] = W[(size_t)(k0+r)*1024 + n0 + tx];
  __syncthreads();
  u16* out = WT + (size_t)blockIdx.z*1024*1024;
  for (int r = ty; r < 32; r += 8)
    out[(size_t)(n0+r)*1024 + k0 + tx] = f32_to_bf16(tile[tx][r]);
}

// vvT rows 64..79: row 64 = 1.0 (ksum ones-row), rows 65..79 = 0.
__global__ __launch_bounds__(256) void init_vvT(u16* __restrict__ vvT) {
  int idx = blockIdx.x*256 + threadIdx.x;       // 1,048,576 threads x 8 elems
  int p = idx >> 14, rem = idx & 16383;
  int row = 64 + (rem >> 10), col8 = (rem & 1023) * 8;
  u16 v = (row == 64) ? (u16)0x3F80 : (u16)0;
  u16x8 o = {v,v,v,v,v,v,v,v};
  *(u16x8*)(vvT + ((size_t)p*80 + row)*8192 + col8) = o;
}

// ================= 256x256 8-phase GEMM (T1+T2+T3+T4+T5) =================
// 512 threads = 8 waves (2M x 4N). BK=64, K=1024 (16 tiles). LDS 128KB.
// Swizzle: LDS[row][slot] holds G[row][slot ^ (row&7)] (slot = 16B unit).
// Read-ahead schedule (one phase before use, compiler-managed lgkmcnt):
//   ph0: [rd af0,b0 (safe: ph3 wait synced A0/B0)] issue A0' vmcnt(4) BAR
//        [rd b1 (B1(kt) just visible; lands under MFMA)] MFMA(0,0) BAR
//   ph1: issue B0' vmcnt(4) BAR [rd af1 (A1(kt) visible)] MFMA(0,1) BAR
//   ph2: issue B1' BAR MFMA(1,1) BAR
//   ph3: issue A1' vmcnt(4) (retires A0',B0' -> next ph0 early reads SAFE) BAR MFMA(1,0) BAR
// Tail kt=15: ph0 vmcnt(2) (B1 landed), ph1 vmcnt(0) (A1 landed).
template<int MODE>
__global__ __launch_bounds__(512) void gemm8(const u16* __restrict__ A, const u16* __restrict__ WT,
    const float* __restrict__ bq, const float* __restrict__ bk, const float* __restrict__ bv,
    u16* __restrict__ qf, u16* __restrict__ kfT, u16* __restrict__ vvT,
    float* __restrict__ fout) {
  extern __shared__ u16 lds[];
  const int z = (MODE==0) ? blockIdx.y : 3;
  const u16* Bt = WT + (size_t)z*1048576;
  int bid = blockIdx.x;
  int swz = (bid & 7)*64 + (bid >> 3);        // 512 blocks, bijective XCD swizzle
  int rb = swz >> 2, cb = swz & 3;
  const int gm0 = rb*256, gn0 = cb*256;
  const int t = threadIdx.x, w = t>>6, l = t&63;
  const int wm = w>>2, wn = w&3;
  const int lrow = l & 15, lks = l >> 4;
  const int csw = (l&7) ^ (l>>3);             // pre-swizzled source slot
  const u16* aBase = A  + (size_t)(gm0 + w*8 + (l>>3))*1024 + csw*8;
  const u16* bBase = Bt + (size_t)(gn0 + w*8 + (l>>3))*1024 + csw*8;

  f32x4 acc[2][2][4][2];
  const f32x4 vzero = {0.f,0.f,0.f,0.f};
  #pragma unroll
  for (int a0=0;a0<2;++a0)
    #pragma unroll
    for (int b0i=0;b0i<2;++b0i)
      #pragma unroll
      for (int c0=0;c0<4;++c0)
        #pragma unroll
        for (int d0=0;d0<2;++d0) acc[a0][b0i][c0][d0] = vzero;

  // prologue: stage full tile 0 into buf0
  #pragma unroll
  for (int half=0; half<2; ++half)
    #pragma unroll
    for (int j=0;j<2;++j) {
      g2lds16(aBase + (half*128 + j*64)*1024, (char*)lds + half*16384 + j*8192 + w*1024);
      g2lds16(bBase + (half*128 + j*64)*1024, (char*)lds + 65536 + half*16384 + j*8192 + w*1024);
    }
  asm volatile("s_waitcnt vmcnt(0)" ::: "memory");
  __builtin_amdgcn_s_barrier();
  asm volatile("" ::: "memory");

  for (int kt = 0; kt < 16; ++kt) {
    const int buf = kt & 1;
    const char* Ab = (const char*)lds + buf*32768;
    const char* Bb = (const char*)lds + 65536 + buf*32768;
    char* An = (char*)lds + (buf^1)*32768;
    char* Bn = (char*)lds + 65536 + (buf^1)*32768;
    const u16* aSrc = aBase + (size_t)(kt+1)*64;
    const u16* bSrc = bBase + (size_t)(kt+1)*64;
    const bool pf = (kt < 15);

    bf16x8 af0[4][2], af1[4][2];  // A fragments for mh=0 / mh=1 (separate regs)
    bf16x8 b0[2][2], b1[2][2];    // B fragments nh=0 / nh=1

    #define LD_A(DST,MH)                                                     \
      _Pragma("unroll")                                                      \
      for (int mi=0;mi<4;++mi) {                                             \
        int row = (MH)*128 + wm*64 + mi*16 + lrow;                           \
        _Pragma("unroll")                                                    \
        for (int kx=0;kx<2;++kx)                                             \
          DST[mi][kx] = *(const bf16x8*)(Ab + row*128 + (((kx*4+lks) ^ (row&7))<<4)); \
      }
    #define LD_B(DST,NH)                                                     \
      _Pragma("unroll")                                                      \
      for (int ni=0;ni<2;++ni) {                                             \
        int row = (NH)*128 + wn*32 + ni*16 + lrow;                           \
        _Pragma("unroll")                                                    \
        for (int kx=0;kx<2;++kx)                                             \
          DST[ni][kx] = *(const bf16x8*)(Bb + row*128 + (((kx*4+lks) ^ (row&7))<<4)); \
      }
    #define MFMA16(MH,NH,AF,BF)                                              \
      __builtin_amdgcn_s_setprio(1);                                         \
      _Pragma("unroll")                                                      \
      for (int mi=0;mi<4;++mi)                                               \
        _Pragma("unroll")                                                    \
        for (int ni=0;ni<2;++ni) {                                           \
          acc[MH][NH][mi][ni] = __builtin_amdgcn_mfma_f32_16x16x32_bf16(AF[mi][0], BF[ni][0], acc[MH][NH][mi][ni], 0,0,0); \
          acc[MH][NH][mi][ni] = __builtin_amdgcn_mfma_f32_16x16x32_bf16(AF[mi][1], BF[ni][1], acc[MH][NH][mi][ni], 0,0,0); \
        }                                                                    \
      __builtin_amdgcn_s_setprio(0);                                         \
      __builtin_amdgcn_s_barrier();                                          \
      asm volatile("" ::: "memory");

    // ---- phase 0 ----
    LD_A(af0, 0); LD_B(b0, 0);        // safe: A0/B0(kt) synced by kt-1.ph3 wait (or prologue)
    if (pf) { g2lds16(aSrc, An + w*1024); g2lds16(aSrc + 64*1024, An + 8192 + w*1024); }
    if (pf) { asm volatile("s_waitcnt vmcnt(4)" ::: "memory"); }   // retires B1(kt)
    else    { asm volatile("s_waitcnt vmcnt(2)" ::: "memory"); }
    __builtin_amdgcn_s_barrier();
    asm volatile("" ::: "memory");
    LD_B(b1, 1);                       // lands under MFMA; used ph1
    MFMA16(0, 0, af0, b0);

    // ---- phase 1 ----
    if (pf) { g2lds16(bSrc, Bn + w*1024); g2lds16(bSrc + 64*1024, Bn + 8192 + w*1024); }
    if (pf) { asm volatile("s_waitcnt vmcnt(4)" ::: "memory"); }   // retires A1(kt)
    else    { asm volatile("s_waitcnt vmcnt(0)" ::: "memory"); }
    __builtin_amdgcn_s_barrier();
    asm volatile("" ::: "memory");
    LD_A(af1, 1);                      // lands under MFMA; used ph2/ph3
    MFMA16(0, 1, af0, b1);

    // ---- phase 2 ----
    if (pf) { g2lds16(bSrc + 128*1024, Bn + 16384 + w*1024); g2lds16(bSrc + 192*1024, Bn + 24576 + w*1024); }
    __builtin_amdgcn_s_barrier();
    asm volatile("" ::: "memory");
    MFMA16(1, 1, af1, b1);

    // ---- phase 3 ----
    if (pf) { g2lds16(aSrc + 128*1024, An + 16384 + w*1024); g2lds16(aSrc + 192*1024, An + 24576 + w*1024); }
    if (pf) { asm volatile("s_waitcnt vmcnt(4)" ::: "memory"); }   // retires A0,B0(kt+1): next ph0 early reads safe
    __builtin_amdgcn_s_barrier();
    asm volatile("" ::: "memory");
    MFMA16(1, 0, af1, b0);

    #undef LD_A
    #undef LD_B
    #undef MFMA16
  }

  // epilogue
  if (MODE == 0) {
    const float* bias = z==0 ? bq : (z==1 ? bk : bv);
    const bool feat = (z < 2);
    if (z == 0) {
      #pragma unroll
      for (int mh=0;mh<2;++mh)
        #pragma unroll
        for (int nh=0;nh<2;++nh)
          #pragma unroll
          for (int mi=0;mi<4;++mi)
            #pragma unroll
            for (int ni=0;ni<2;++ni) {
              int n = gn0 + nh*128 + wn*32 + ni*16 + lrow;
              float bn = bias[n];
              int h = n>>6, hd = n&63;
              int mbase = gm0 + mh*128 + wm*64 + mi*16 + (lks<<2);
              #pragma unroll
              for (int r=0;r<4;++r) {
                int m = mbase + r;
                float val = acc[mh][nh][mi][ni][r] + bn;
                val = val>0.f ? val+1.f : __expf(val);
                qf[((size_t)((m>>13)*16 + h)*8192 + (m&8191))*64 + hd] = f32_to_bf16(val);
              }
            }
    } else {
      // transposed: out[p][hd][s], pair stride rows = 64 (kfT) / 80 (vvT)
      u16* outp = (z==1) ? kfT : vvT;
      const size_t prow = (z==1) ? 64 : 80;
      #pragma unroll
      for (int mh=0;mh<2;++mh)
        #pragma unroll
        for (int nh=0;nh<2;++nh)
          #pragma unroll
          for (int mi=0;mi<4;++mi)
            #pragma unroll
            for (int ni=0;ni<2;++ni) {
              int n = gn0 + nh*128 + wn*32 + ni*16 + lrow;
              float bn = bias[n];
              int h = n>>6, hd = n&63;
              int mbase = gm0 + mh*128 + wm*64 + mi*16 + (lks<<2);
              int b_ = mbase >> 13, s = mbase & 8191;
              u16x4 pk;
              #pragma unroll
              for (int r=0;r<4;++r) {
                float val = acc[mh][nh][mi][ni][r] + bn;
                if (feat) val = val>0.f ? val+1.f : __expf(val);
                pk[r] = f32_to_bf16(val);
              }
              *(u16x4*)(outp + ((size_t)(b_*16 + h)*prow + hd)*8192 + s) = pk;
            }
    }
  } else {
    #pragma unroll
    for (int mh=0;mh<2;++mh)
      #pragma unroll
      for (int nh=0;nh<2;++nh)
        #pragma unroll
        for (int mi=0;mi<4;++mi)
          #pragma unroll
          for (int ni=0;ni<2;++ni) {
            int n = gn0 + nh*128 + wn*32 + ni*16 + lrow;
            float bn = bq[n];   // MODE1: bq carries bo
            int mbase = gm0 + mh*128 + wm*64 + mi*16 + (lks<<2);
            #pragma unroll
            for (int r=0;r<4;++r) {
              int m = mbase + r;
              fout[(size_t)m*1024 + n] = acc[mh][nh][mi][ni][r] + bn;
            }
          }
  }
}

// ---------------- kv via MFMA: C[m][d] = sum_s vvT[m][s]*kfT[d][s] ----------------
__global__ __launch_bounds__(256) void kv_mfma(const u16* __restrict__ kfT, const u16* __restrict__ vvT,
                                               float* __restrict__ pkv) {
  __shared__ __align__(16) u16 lA[80*256];   // 40KB vvT tile
  __shared__ __align__(16) u16 lB[64*256];   // 32KB kfT tile
  const int p = blockIdx.x, c = blockIdx.y;
  const int t = threadIdx.x, w = t>>6, l = t&63;
  const int srow = t >> 5;                   // staged row within 8-row group
  const int csw = (t&31) ^ ((t>>5)&7);       // pre-swizzled source slot
  const u16* aRow = vvT + ((size_t)p*80 + srow)*8192 + (size_t)c*512 + csw*8;
  const u16* bRow = kfT + ((size_t)p*64 + srow)*8192 + (size_t)c*512 + csw*8;

  f32x4 acc5[5];
  const f32x4 vzero = {0.f,0.f,0.f,0.f};
  #pragma unroll
  for (int mi=0;mi<5;++mi) acc5[mi] = vzero;

  for (int sub = 0; sub < 2; ++sub) {
    const size_t so = (size_t)sub*256;
    #pragma unroll
    for (int i=0;i<10;++i)
      g2lds16(aRow + (size_t)i*8*8192 + so, (char*)lA + i*4096 + t*16);
    #pragma unroll
    for (int i=0;i<8;++i)
      g2lds16(bRow + (size_t)i*8*8192 + so, (char*)lB + i*4096 + t*16);
    asm volatile("s_waitcnt vmcnt(0)" ::: "memory");
    __builtin_amdgcn_s_barrier();
    asm volatile("" ::: "memory");
    #pragma unroll
    for (int ks=0;ks<8;++ks) {
      const int brow = w*16 + (l&15);
      const int slot = ks*4 + (l>>4);
      bf16x8 bfr = *(const bf16x8*)((const char*)lB + brow*512 + ((slot ^ (brow&7))<<4));
      #pragma unroll
      for (int mi=0;mi<5;++mi) {
        const int arow = mi*16 + (l&15);
        bf16x8 afr = *(const bf16x8*)((const char*)lA + arow*512 + ((slot ^ (arow&7))<<4));
        acc5[mi] = __builtin_amdgcn_mfma_f32_16x16x32_bf16(afr, bfr, acc5[mi], 0,0,0);
      }
    }
    __builtin_amdgcn_s_barrier();
    asm volatile("" ::: "memory");
  }

  float* po = pkv + ((size_t)p*16 + c)*5120;
  #pragma unroll
  for (int mi=0;mi<5;++mi)
    #pragma unroll
    for (int r=0;r<4;++r)
      po[(mi*16 + (l>>4)*4 + r)*64 + w*16 + (l&15)] = acc5[mi][r];
}

// ---------------- reduce partials -> bkv[p][80][64] bf16 ----------------
__global__ __launch_bounds__(256) void kv_reduce(const float* __restrict__ pkv, u16* __restrict__ bkv) {
  int p = blockIdx.x, t = threadIdx.x;
  for (int i = t; i < 5120; i += 256) {
    float s = 0.f;
    for (int c = 0; c < 16; ++c) s += pkv[((size_t)p*16 + c)*5120 + i];
    bkv[(size_t)p*5120 + i] = f32_to_bf16(s);
  }
}

// ---------------- y = z * (qf @ kv^T), den fused as extra N column ----------------
__global__ __launch_bounds__(256) void y_gemm(const u16* __restrict__ qf, const u16* __restrict__ bkv,
                                              u16* __restrict__ y) {
  __shared__ __align__(16) u16 As[256*64];
  __shared__ __align__(16) u16 Bs[80*64];
  int p = blockIdx.x, rb = blockIdx.y;
  int t = threadIdx.x, wave = t >> 6, lane = t & 63;
  const u16* aslab = qf + ((size_t)p*8192 + (size_t)rb*256)*64;
  for (int i = t*8; i < 5120; i += 2048)
    *(int4*)&Bs[i] = *(const int4*)&bkv[(size_t)p*5120 + i];
  #pragma unroll
  for (int it = 0; it < 8; ++it)
    g2lds16(aslab + it*2048 + t*8, (char*)As + it*4096 + wave*1024);
  __syncthreads();
  const f32x4 vzero = {0.f,0.f,0.f,0.f};
  f32x4 acc[4][5];
  #pragma unroll
  for (int mi=0;mi<4;++mi)
    #pragma unroll
    for (int ni=0;ni<5;++ni) acc[mi][ni] = vzero;
  #pragma unroll
  for (int kk = 0; kk < 64; kk += 32) {
    bf16x8 af[4], bfr[5];
    #pragma unroll
    for (int mi=0;mi<4;++mi)
      af[mi] = *(const bf16x8*)&As[(wave*64 + mi*16 + (lane&15))*64 + kk + (lane>>4)*8];
    #pragma unroll
    for (int ni=0;ni<5;++ni)
      bfr[ni] = *(const bf16x8*)&Bs[(ni*16 + (lane&15))*64 + kk + (lane>>4)*8];
    #pragma unroll
    for (int mi=0;mi<4;++mi)
      #pragma unroll
      for (int ni=0;ni<5;++ni)
        acc[mi][ni] = __builtin_amdgcn_mfma_f32_16x16x32_bf16(af[mi], bfr[ni], acc[mi][ni], 0, 0, 0);
  }
  int b_ = p >> 4, h = p & 15;
  #pragma unroll
  for (int mi=0;mi<4;++mi) {
    #pragma unroll
    for (int r=0;r<4;++r) {
      float den = __shfl(acc[mi][4][r], lane & 48);
      float zf = 1.0f / (den + 1e-6f);
      int lq = rb*256 + wave*64 + mi*16 + ((lane>>4)<<2) + r;
      size_t rowbase = ((size_t)(b_*8192 + lq)*16 + h)*64;
      #pragma unroll
      for (int ni=0;ni<4;++ni)
        y[rowbase + ni*16 + (lane&15)] = f32_to_bf16(acc[mi][ni][r] * zf);
    }
  }
}

extern "C" void kernel_launch(void* const* d_in, const int* in_sizes, int n_in,
                              void* d_out, int out_size, void* d_ws, size_t ws_size,
                              hipStream_t stream) {
  const float* x  = (const float*)d_in[0];
  const float* Wq = (const float*)d_in[1];
  const float* bq = (const float*)d_in[2];
  const float* Wk = (const float*)d_in[3];
  const float* bk = (const float*)d_in[4];
  const float* Wv = (const float*)d_in[5];
  const float* bv = (const float*)d_in[6];
  const float* Wo = (const float*)d_in[7];
  const float* bo = (const float*)d_in[8];
  float* out = (float*)d_out;
  char* ws = (char*)d_ws;

  u16*  xb  = (u16*)(ws);                    // 64MB; later aliased by pkv, then yb
  u16*  WT  = (u16*)(ws + 67108864);         //  8MB
  u16*  qf  = (u16*)(ws + 75497472);         // 64MB [64p][8192][64]
  u16*  kfT = (u16*)(ws + 142606336);        // 64MB [64p][64][8192]
  u16*  vvT = (u16*)(ws + 209715200);        // 80MB [64p][80][8192] (row64=1, 65-79=0)
  u16*  bkv = (u16*)(ws + 293601280);        // 640KB [64p][80][64]
  float* pkv = (float*)(ws);                 // 21MB, aliases xb (dead after gemm8<0>)
  u16*  yb  = xb;                            // aliases xb/pkv (written after pkv consumed)

  auto kq = gemm8<0>; auto ko = gemm8<1>;
  hipFuncSetAttribute((const void*)kq, hipFuncAttributeMaxDynamicSharedMemorySize, 131072);
  hipFuncSetAttribute((const void*)ko, hipFuncAttributeMaxDynamicSharedMemorySize, 131072);

  cvt_x<<<2048, 256, 0, stream>>>(x, xb);
  cvt_wt<<<dim3(32,32,4), dim3(32,8), 0, stream>>>(Wq, Wk, Wv, Wo, WT);
  init_vvT<<<4096, 256, 0, stream>>>(vvT);
  gemm8<0><<<dim3(512,3), 512, 131072, stream>>>(xb, WT, bq, bk, bv, qf, kfT, vvT, nullptr);
  kv_mfma<<<dim3(64,16), 256, 0, stream>>>(kfT, vvT, pkv);
  kv_reduce<<<64, 256, 0, stream>>>(pkv, bkv);
  y_gemm<<<dim3(64,32), 256, 0, stream>>>(qf, bkv, yb);
  gemm8<1><<<dim3(512,1), 512, 131072, stream>>>(yb, WT, bo, nullptr, nullptr, nullptr, nullptr, nullptr, out);
}